// Round 14
// baseline (637.001 us; speedup 1.0000x reference)
//
#include <hip/hip_runtime.h>
#include <hip/hip_bf16.h>
#include <math.h>

#define DI __device__ __forceinline__
#define AS1 __attribute__((address_space(1)))
#define AS3 __attribute__((address_space(3)))

static constexpr int  B_ = 4, C_ = 256, N_ = 1024, L_ = 12, BL_ = 48;
static constexpr long SLAB = (long)N_ * C_;          // 262144 elems per (b,l)
static constexpr long TOT  = (long)BL_ * SLAB;       // 12,582,912 elems

typedef __attribute__((ext_vector_type(8))) short bf16x8;
typedef __attribute__((ext_vector_type(4))) float f32x4;
typedef __attribute__((ext_vector_type(4))) uint u32x4;

DI float b2f(uint hw) { return __builtin_bit_cast(float, (hw & 0xffffu) << 16); }
DI ushort f2b(float f) {
    uint u = __builtin_bit_cast(uint, f);
    u += 0x7FFFu + ((u >> 16) & 1u);
    return (ushort)(u >> 16);
}
DI uint pack2(float a, float b) {
    __hip_bfloat162 h = __float22bfloat162_rn(make_float2(a, b));
    uint r;
    __builtin_memcpy(&r, &h, 4);
    return r;
}
DI float fexp2(float x) {
#if __has_builtin(__builtin_amdgcn_exp2f)
    return __builtin_amdgcn_exp2f(x);
#else
    return __expf(x * 0.6931471805599453f);
#endif
}

DI void gload16(const void* g, void* l) {
    __builtin_amdgcn_global_load_lds((AS1 uint*)g, (AS3 uint*)l, 16, 0, 0);
}

// ---------------- block reductions (256 threads, 4 waves) ----------------
DI float block_sum256(float v, float* sc) {
    #pragma unroll
    for (int o = 32; o > 0; o >>= 1) v += __shfl_xor(v, o, 64);
    int wid = threadIdx.x >> 6;
    __syncthreads();
    if ((threadIdx.x & 63) == 0) sc[wid] = v;
    __syncthreads();
    return sc[0] + sc[1] + sc[2] + sc[3];
}
DI float block_max256(float v, float* sc) {
    #pragma unroll
    for (int o = 32; o > 0; o >>= 1) v = fmaxf(v, __shfl_xor(v, o, 64));
    int wid = threadIdx.x >> 6;
    __syncthreads();
    if ((threadIdx.x & 63) == 0) sc[wid] = v;
    __syncthreads();
    return fmaxf(fmaxf(sc[0], sc[1]), fmaxf(sc[2], sc[3]));
}

// ---------------- adp = softmax(relu(nv1@nv2), axis=1), bf16 out ----------------
__global__ __launch_bounds__(256) void k_adp(const float* __restrict__ nv1,
                                             const float* __restrict__ nv2,
                                             ushort* __restrict__ adp) {
    __shared__ float r[6];
    __shared__ float sc[4];
    int row = blockIdx.x, tid = threadIdx.x;
    if (tid < 6) r[tid] = nv1[row * 6 + tid];
    __syncthreads();
    float e[4];
    #pragma unroll
    for (int q = 0; q < 4; q++) {
        int j = tid + q * 256;
        float s = 0.f;
        #pragma unroll
        for (int k = 0; k < 6; k++) s += r[k] * nv2[k * 1024 + j];
        e[q] = s > 0.f ? s : 0.f;
    }
    float m = fmaxf(fmaxf(e[0], e[1]), fmaxf(e[2], e[3]));
    m = block_max256(m, sc);
    float ps = 0.f;
    #pragma unroll
    for (int q = 0; q < 4; q++) { e[q] = __expf(e[q] - m); ps += e[q]; }
    ps = block_sum256(ps, sc);
    float rinv = 1.f / ps;
    #pragma unroll
    for (int q = 0; q < 4; q++) adp[(long)row * 1024 + tid + q * 256] = f2b(e[q] * rinv);
}

// ------- transpose in: x[b][c][n][l] -> Xb[(b*12+l)][n][c] bf16 + fp32 copy -------
__global__ __launch_bounds__(256) void k_tin(const float* __restrict__ x,
                                             ushort* __restrict__ xb,
                                             float* __restrict__ xf) {
    __shared__ float t[64][65];
    int nl0 = blockIdx.x * 64, c0 = blockIdx.y * 64, b = blockIdx.z;
    int lx = threadIdx.x & 63, ly = threadIdx.x >> 6;
    #pragma unroll
    for (int i = 0; i < 16; i++) {
        int c = c0 + ly + i * 4;
        t[ly + i * 4][lx] = x[(long)(b * 256 + c) * 12288 + nl0 + lx];
    }
    __syncthreads();
    #pragma unroll
    for (int i = 0; i < 16; i++) {
        int nl = nl0 + ly + i * 4;
        int n = nl / 12, l = nl % 12;
        long idx = ((long)(b * 12 + l) * 1024 + n) * 256 + c0 + lx;
        float v = t[lx][ly + i * 4];
        xb[idx] = f2b(v);
        xf[idx] = v;
    }
}

// ---------------- per-bl transpose Xb[n][c] -> XTT[c][n] (bf16) ----------------
__global__ __launch_bounds__(256) void k_xtt(const ushort* __restrict__ X,
                                             ushort* __restrict__ XT) {
    __shared__ ushort t[64][68];
    int bl = blockIdx.z;
    int n0 = blockIdx.x * 64, c0 = blockIdx.y * 64;
    int lx = threadIdx.x & 63, ly = threadIdx.x >> 6;
    const ushort* Xp = X + (long)bl * SLAB;
    #pragma unroll
    for (int i = 0; i < 16; i++)
        t[ly + i * 4][lx] = Xp[(long)(n0 + ly + i * 4) * 256 + c0 + lx];
    __syncthreads();
    ushort* Tp = XT + (long)bl * SLAB;
    #pragma unroll
    for (int i = 0; i < 16; i++)
        Tp[(long)(c0 + ly + i * 4) * 1024 + n0 + lx] = t[lx][ly + i * 4];
}

// -------- GAT weight transposes 256x256 fp32 [c][o] -> bf16 [o][c] --------
__global__ __launch_bounds__(256) void k_wt2(const float* __restrict__ S0, ushort* __restrict__ D0,
                                             const float* __restrict__ S1, ushort* __restrict__ D1) {
    __shared__ float t[64][65];
    const float* S = blockIdx.z ? S1 : S0;
    ushort* D = blockIdx.z ? D1 : D0;
    int c0 = blockIdx.x * 64, o0 = blockIdx.y * 64;
    int lx = threadIdx.x & 63, ly = threadIdx.x >> 6;
    #pragma unroll
    for (int i = 0; i < 16; i++)
        t[ly + i * 4][lx] = S[(long)(c0 + ly + i * 4) * 256 + o0 + lx];
    __syncthreads();
    #pragma unroll
    for (int i = 0; i < 16; i++)
        D[(long)(o0 + ly + i * 4) * 256 + c0 + lx] = f2b(t[lx][ly + i * 4]);
}

// ---------------- fp32 -> bf16 straight cast ----------------
__global__ __launch_bounds__(256) void k_wconv(const float* __restrict__ S, ushort* __restrict__ D) {
    long i = (long)blockIdx.x * 256 + threadIdx.x;
    D[i] = f2b(S[i]);
}

// ------- interleaved GLU weights: WGI[p*32+q] = (q<16 ? Wg1 : Wg2) row p*16+q%16 -------
__global__ __launch_bounds__(256) void k_wgi(const float* __restrict__ W1, const float* __restrict__ b1,
                                             const float* __restrict__ W2, const float* __restrict__ b2,
                                             ushort* __restrict__ WGI, float* __restrict__ BI) {
    int n = blockIdx.x, p = n >> 5, q = n & 31;
    const float* src = (q < 16) ? W1 + (long)(p * 16 + q) * 256
                                : W2 + (long)(p * 16 + q - 16) * 256;
    WGI[(long)n * 256 + threadIdx.x] = f2b(src[threadIdx.x]);
    if (threadIdx.x == 0) BI[n] = (q < 16) ? b1[p * 16 + q] : b2[p * 16 + q - 16];
}

// ----- va = W @ a pair -----
__global__ __launch_bounds__(256) void k_va(const float* __restrict__ W, const float* __restrict__ a,
                                            float* __restrict__ va) {
    __shared__ float sc[4];
    int c = blockIdx.x, t = threadIdx.x;
    float w = W[(long)c * 256 + t];
    float s1 = block_sum256(w * a[t], sc);
    float s2 = block_sum256(w * a[256 + t], sc);
    if (t == 0) { va[c] = s1; va[256 + c] = s2; }
}

// ------- weight/bias prep: wt[n][c] = w[c][n]+1, bt[n][c] = b[c][n] -------
__global__ __launch_bounds__(256) void k_wtprep(const float* __restrict__ w,
                                                const float* __restrict__ b,
                                                float* __restrict__ wt,
                                                float* __restrict__ bt) {
    int n = blockIdx.x, c = threadIdx.x;
    wt[(long)n * 256 + c] = w[(long)c * 1024 + n] + 1.f;
    bt[(long)n * 256 + c] = b[(long)c * 1024 + n];
}

// ------- pack mask bits -------
__global__ __launch_bounds__(256) void k_maskpack(const int* __restrict__ dg,
                                                  uint* __restrict__ maskw) {
    int w = blockIdx.x * 256 + threadIdx.x;
    int row = w >> 5, wo = w & 31;
    uint m = 0;
    #pragma unroll
    for (int b = 0; b < 32; b++)
        m |= (dg[(long)row * 1024 + wo * 32 + b] > 0 ? 1u : 0u) << b;
    maskw[w] = m;
}

// ------- bf16 MFMA GEMM, 2-phase pipelined -------
// GLU=0: plain (+bias) -> Cf/Cb. GLU=1: interleaved g1/g2, h=g1*sig(g2) -> Cb.
// GLU=2: finpre fusion: v=(acc+bias + (FA-m1)*r1)*WTp + BTp -> Cf, + LN partials.
template<int NPAIR, int GLU>
__global__ __launch_bounds__(256) void k_bgemm(
    const ushort* __restrict__ A0, long sA0,
    const ushort* __restrict__ A1, long sA1,
    int lda, int K0, int KK,
    const ushort* __restrict__ Bt, long sBt,
    const float* __restrict__ bias,
    float* __restrict__ Cf, ushort* __restrict__ Cb, long sC,
    const float* __restrict__ biasi,
    const float* __restrict__ FA, const float2* __restrict__ ST1,
    const float* __restrict__ WTp, const float* __restrict__ BTp,
    float2* __restrict__ partOut) {
    __shared__ ushort As[2][128 * 32];
    __shared__ ushort Bs[2][128 * 32];
    __shared__ float sc[4];
    const int tid = threadIdx.x;
    const int bl = blockIdx.z;
    const int m0 = blockIdx.x * 128, n0 = blockIdx.y * 128;
    const int N = gridDim.y * 128;
    const int lane = tid & 63, w = tid >> 6;
    const int wm = (w >> 1) * 64, wn = (w & 1) * 64;
    const int sr = tid >> 2, sk = (tid & 3) * 8;
    const int fr = lane & 15, fk = (lane >> 4) * 8;
    f32x4 acc[4][4] = {};
    const ushort* Ab0 = A0 + (long)bl * sA0;
    const ushort* Ab1 = (NPAIR == 2) ? A1 + (long)bl * sA1 : nullptr;
    const ushort* Bb = Bt + (long)bl * sBt;

    auto stage = [&](int buf, int k0) {
        const ushort* Asrc = Ab0; int kl = k0;
        if (NPAIR == 2 && k0 >= K0) { Asrc = Ab1; kl = k0 - K0; }
        gload16(&Asrc[(long)(m0 + sr) * lda + kl + sk],      &As[buf][sr * 32 + sk]);
        gload16(&Asrc[(long)(m0 + sr + 64) * lda + kl + sk], &As[buf][(sr + 64) * 32 + sk]);
        gload16(&Bb[(long)(n0 + sr) * KK + k0 + sk],         &Bs[buf][sr * 32 + sk]);
        gload16(&Bb[(long)(n0 + sr + 64) * KK + k0 + sk],    &Bs[buf][(sr + 64) * 32 + sk]);
    };
    auto compute = [&](int buf) {
        bf16x8 af[4], bg[4];
        #pragma unroll
        for (int i = 0; i < 4; i++) {
            af[i] = *(const bf16x8*)&As[buf][(wm + i * 16 + fr) * 32 + fk];
            bg[i] = *(const bf16x8*)&Bs[buf][(wn + i * 16 + fr) * 32 + fk];
        }
        #pragma unroll
        for (int i = 0; i < 4; i++)
            #pragma unroll
            for (int j = 0; j < 4; j++)
                acc[i][j] = __builtin_amdgcn_mfma_f32_16x16x32_bf16(af[i], bg[j], acc[i][j], 0, 0, 0);
    };

    stage(0, 0);
    __syncthreads();
    int cur = 0;
    for (int k0 = 32; k0 < KK; k0 += 32) {
        stage(cur ^ 1, k0);
        compute(cur);
        __syncthreads();
        cur ^= 1;
    }
    compute(cur);

    const int cn = lane & 15, rb = (lane >> 4) * 4;
    if (GLU == 1) {
        #pragma unroll
        for (int nt = 0; nt < 4; nt += 2) {
            int n1 = n0 + wn + nt * 16 + cn;
            int hcol = ((n1 >> 5) << 4) + cn;
            float b1 = biasi[n1], b2 = biasi[n1 + 16];
            #pragma unroll
            for (int i = 0; i < 4; i++) {
                #pragma unroll
                for (int r = 0; r < 4; r++) {
                    int m = m0 + wm + i * 16 + rb + r;
                    float g1 = acc[i][nt][r] + b1;
                    float g2 = acc[i][nt + 1][r] + b2;
                    float h = g1 / (1.f + __expf(-g2));
                    Cb[(long)bl * sC + (long)m * 256 + hcol] = f2b(h);
                }
            }
        }
    } else if (GLU == 2) {
        float2 st = ST1[bl];
        float ssum = 0.f, qsum = 0.f;
        #pragma unroll
        for (int j = 0; j < 4; j++) {
            int n = n0 + wn + j * 16 + cn;
            float bv = bias[n];
            #pragma unroll
            for (int i = 0; i < 4; i++) {
                #pragma unroll
                for (int r = 0; r < 4; r++) {
                    int m = m0 + wm + i * 16 + rb + r;
                    long idx = (long)bl * sC + (long)m * N + n;
                    float xn = (FA[idx] - st.x) * st.y;
                    float v = (acc[i][j][r] + bv + xn) * WTp[m * 256 + n] + BTp[m * 256 + n];
                    Cf[idx] = v;
                    ssum += v;
                    qsum += v * v;
                }
            }
        }
        ssum = block_sum256(ssum, sc);
        qsum = block_sum256(qsum, sc);
        if (tid == 0)
            partOut[bl * 16 + blockIdx.x * 2 + blockIdx.y] = make_float2(ssum, qsum);
    } else {
        #pragma unroll
        for (int j = 0; j < 4; j++) {
            int n = n0 + wn + j * 16 + cn;
            float bv = bias ? bias[n] : 0.f;
            #pragma unroll
            for (int i = 0; i < 4; i++) {
                #pragma unroll
                for (int r = 0; r < 4; r++) {
                    int m = m0 + wm + i * 16 + rb + r;
                    float v = acc[i][j][r] + bv;
                    long idx = (long)bl * sC + (long)m * N + n;
                    if (Cf) Cf[idx] = v;
                    if (Cb) Cb[idx] = f2b(v);
                }
            }
        }
    }
}

// ---------------- w1/w2 GEMV ----------------
__global__ __launch_bounds__(256) void k_dots(const ushort* __restrict__ X,
                                              const float* __restrict__ va,
                                              float* __restrict__ o1,
                                              float* __restrict__ o2) {
    int wid = threadIdx.x >> 6, lane = threadIdx.x & 63;
    long row = (long)blockIdx.x * 4 + wid;
    uint2 xv = *(const uint2*)(X + row * 256 + lane * 4);
    float x0 = b2f(xv.x), x1 = b2f(xv.x >> 16), x2 = b2f(xv.y), x3 = b2f(xv.y >> 16);
    float4 v1 = *(const float4*)&va[lane * 4];
    float4 v2 = *(const float4*)&va[256 + lane * 4];
    float s1 = x0 * v1.x + x1 * v1.y + x2 * v1.z + x3 * v1.w;
    float s2 = x0 * v2.x + x1 * v2.y + x2 * v2.z + x3 * v2.w;
    #pragma unroll
    for (int o = 32; o > 0; o >>= 1) { s1 += __shfl_xor(s1, o, 64); s2 += __shfl_xor(s2, o, 64); }
    if (lane == 0) { o1[row] = s1; o2[row] = s2; }
}

// ------- per-bl global max of w2 -------
__global__ __launch_bounds__(256) void k_w2max(const float* __restrict__ w2v,
                                               float* __restrict__ w2m) {
    __shared__ float sc[4];
    int bl = blockIdx.x;
    float4 v = *(const float4*)&w2v[(long)bl * 1024 + threadIdx.x * 4];
    float m = fmaxf(fmaxf(v.x, v.y), fmaxf(v.z, v.w));
    m = block_max256(m, sc);
    if (threadIdx.x == 0) w2m[bl] = m;
}

// One ks step: mask word MW (compile-time uint4 member), exp-free p, LUT AND, MFMA.
#define KSB(KS_, MW0, MW1, MW2, MW3)                                           \
    do {                                                                       \
        const int ksv = (KS_);                                                 \
        float4 ea = *(const float4*)&w2E[ksv * 32 + fk8];                      \
        float4 eb = *(const float4*)&w2E[ksv * 32 + fk8 + 4];                  \
        float4 fa = *(const float4*)&w2F[ksv * 32 + fk8];                      \
        float4 fb = *(const float4*)&w2F[ksv * 32 + fk8 + 4];                  \
        bf16x8 bg0 = *(const bf16x8*)&bp[(long)(wn + 0 * 16 + fr) * 1024 + ksv * 32 + fk8]; \
        bf16x8 bg1 = *(const bf16x8*)&bp[(long)(wn + 1 * 16 + fr) * 1024 + ksv * 32 + fk8]; \
        bf16x8 bg2 = *(const bf16x8*)&bp[(long)(wn + 2 * 16 + fr) * 1024 + ksv * 32 + fk8]; \
        bf16x8 bg3 = *(const bf16x8*)&bp[(long)(wn + 3 * 16 + fr) * 1024 + ksv * 32 + fk8]; \
        const uint mws[4] = {0, 0, 0, 0};  (void)mws;                          \
        _Pragma("unroll")                                                      \
        for (int mt = 0; mt < 4; mt++) {                                       \
            uint mby = ((mt == 0 ? (MW0) : mt == 1 ? (MW1) : mt == 2 ? (MW2)   \
                                                           : (MW3)) >> fg8) & 0xffu; \
            float p0 = fmaxf(c1[mt] * ea.x, c2[mt] * fa.x);                    \
            float p1 = fmaxf(c1[mt] * ea.y, c2[mt] * fa.y);                    \
            float p2 = fmaxf(c1[mt] * ea.z, c2[mt] * fa.z);                    \
            float p3 = fmaxf(c1[mt] * ea.w, c2[mt] * fa.w);                    \
            float p4 = fmaxf(c1[mt] * eb.x, c2[mt] * fb.x);                    \
            float p5 = fmaxf(c1[mt] * eb.y, c2[mt] * fb.y);                    \
            float p6 = fmaxf(c1[mt] * eb.z, c2[mt] * fb.z);                    \
            float p7 = fmaxf(c1[mt] * eb.w, c2[mt] * fb.w);                    \
            u32x4 av;                                                          \
            av[0] = pack2(p0, p1) & mlut[mby & 3];                             \
            av[1] = pack2(p2, p3) & mlut[(mby >> 2) & 3];                      \
            av[2] = pack2(p4, p5) & mlut[(mby >> 4) & 3];                      \
            av[3] = pack2(p6, p7) & mlut[(mby >> 6) & 3];                      \
            bf16x8 af = __builtin_bit_cast(bf16x8, av);                        \
            acc_s[mt] = __builtin_amdgcn_mfma_f32_16x16x32_bf16(af, onesf, acc_s[mt], 0, 0, 0); \
            acc[mt][0] = __builtin_amdgcn_mfma_f32_16x16x32_bf16(af, bg0, acc[mt][0], 0, 0, 0); \
            acc[mt][1] = __builtin_amdgcn_mfma_f32_16x16x32_bf16(af, bg1, acc[mt][1], 0, 0, 0); \
            acc[mt][2] = __builtin_amdgcn_mfma_f32_16x16x32_bf16(af, bg2, acc[mt][2], 0, 0, 0); \
            acc[mt][3] = __builtin_amdgcn_mfma_f32_16x16x32_bf16(af, bg3, acc[mt][3], 0, 0, 0); \
        }                                                                      \
    } while (0)

// ------- MFMA attention v9: barrier-free, exp-free, b128 mask reads, 4-ks unroll ----
// FUSE=1: epilogue computes as*elu(out)+bs*gcn+x -> Af fp32 + LN partials.
template<int FUSE>
__global__ __launch_bounds__(256, 3) void k_attn_mf(
    const ushort* __restrict__ WhT,   // [48][256][1024] bf16
    const float* __restrict__ w1v, const float* __restrict__ w2v,
    const float* __restrict__ w2m,    // [48]
    const uint* __restrict__ maskw,   // [1024][32]
    ushort* __restrict__ outB,
    const float* __restrict__ gcn, const float* __restrict__ xf,
    const float* __restrict__ alpha,
    float* __restrict__ outF, float2* __restrict__ part) {
    __shared__ float w2E[1024];          // exp2(w2 * log2e)
    __shared__ float w2F[1024];          // exp2(0.2 * w2 * log2e)
    __shared__ uint msk[64 * 36];        // stride 36: 16B-aligned uint4 rows
    __shared__ uint mlut[4];             // 2-bit mask -> halfword AND pattern
    __shared__ float sc[4];
    constexpr float LOG2E = 1.4426950408889634f;
    int d = blockIdx.x;                  // 768 blocks
    int lidx = (d & 7) * 96 + (d >> 3);  // XCD-chunked: 6 bl per XCD
    int bl = lidx >> 4;
    int i0 = (lidx & 15) * 64;
    int tid = threadIdx.x;
    #pragma unroll
    for (int q = 0; q < 4; q++) {
        float v = w2v[(long)bl * 1024 + tid + q * 256];
        w2E[tid + q * 256] = fexp2(v * LOG2E);
        w2F[tid + q * 256] = fexp2(v * (0.2f * LOG2E));
    }
    if (tid < 4) mlut[tid] = ((tid & 1) ? 0x0000FFFFu : 0u) | ((tid & 2) ? 0xFFFF0000u : 0u);
    {   // mask staging: 2048 words, coalesced load, 16B-aligned stores at stride 36
        const uint4* gm = (const uint4*)(maskw + (long)i0 * 32);
        uint4 ma = gm[tid * 2], mb = gm[tid * 2 + 1];
        int r0 = tid >> 2, w0 = (tid & 3) * 8;
        *(uint4*)&msk[r0 * 36 + w0] = ma;
        *(uint4*)&msk[r0 * 36 + w0 + 4] = mb;
    }
    __syncthreads();
    const int lane = tid & 63, w = tid >> 6;
    const int wn = w * 64;
    const int fr = lane & 15, fg = lane >> 4, fk8 = fg * 8;
    const int fg8 = fg * 8;
    const float w2mL = w2m[bl] * LOG2E;
    float c1[4], c2[4];
    #pragma unroll
    for (int mt = 0; mt < 4; mt++) {
        float w1L = w1v[(long)bl * 1024 + i0 + mt * 16 + fr] * LOG2E;
        float e0 = w1L + w2mL;
        float mrL = fmaxf(e0, 0.2f * e0);          // = log2e * leaky(w1+w2max) >= all scores
        c1[mt] = fexp2(w1L - mrL);
        c2[mt] = fexp2(0.2f * w1L - mrL);
    }
    f32x4 acc[4][4] = {};
    f32x4 acc_s[4] = {};
    u32x4 ov; ov[0] = ov[1] = ov[2] = ov[3] = 0x3F803F80u;   // bf16 1.0 pairs
    const bf16x8 onesf = __builtin_bit_cast(bf16x8, ov);
    const ushort* bp = WhT + (long)bl * SLAB;
    #pragma unroll 1
    for (int kg = 0; kg < 8; kg++) {
        // one b128 mask read per (kg, mt): 4 ks worth of words
        uint4 q0 = *(const uint4*)&msk[(0 * 16 + fr) * 36 + kg * 4];
        uint4 q1 = *(const uint4*)&msk[(1 * 16 + fr) * 36 + kg * 4];
        uint4 q2 = *(const uint4*)&msk[(2 * 16 + fr) * 36 + kg * 4];
        uint4 q3 = *(const uint4*)&msk[(3 * 16 + fr) * 36 + kg * 4];
        KSB(kg * 4 + 0, q0.x, q1.x, q2.x, q3.x);
        KSB(kg * 4 + 1, q0.y, q1.y, q2.y, q3.y);
        KSB(kg * 4 + 2, q0.z, q1.z, q2.z, q3.z);
        KSB(kg * 4 + 3, q0.w, q1.w, q2.w, q3.w);
    }
    float as = 0.f, bs = 0.f, ssum = 0.f, qsum = 0.f;
    if (FUSE) { as = 1.f / (1.f + __expf(-alpha[0])); bs = 1.f - as; }
    #pragma unroll
    for (int mt = 0; mt < 4; mt++) {
        #pragma unroll
        for (int r = 0; r < 4; r++) {
            float si = 1.f / acc_s[mt][r];          // own row's sum — no cross-lane
            int i = mt * 16 + fg * 4 + r;
            #pragma unroll
            for (int nt = 0; nt < 4; nt++) {
                int c = wn + nt * 16 + fr;
                float v = acc[mt][nt][r] * si;
                v = (v > 0.f) ? v : __expf(v) - 1.f;       // elu
                long idx = (long)bl * SLAB + (long)(i0 + i) * 256 + c;
                if (FUSE) {
                    float fv = as * v + bs * gcn[idx] + xf[idx];
                    outF[idx] = fv;
                    ssum += fv;
                    qsum += fv * fv;
                } else {
                    outB[idx] = f2b(v);
                }
            }
        }
    }
    if (FUSE) {
        ssum = block_sum256(ssum, sc);
        qsum = block_sum256(qsum, sc);
        if (tid == 0) part[bl * 16 + (lidx & 15)] = make_float2(ssum, qsum);
    }
}

// ------- stats from 16 partials per slab -------
__global__ void k_stats16(const float2* __restrict__ part, float2* __restrict__ stats) {
    int bl = blockIdx.x, t = threadIdx.x;
    float s = 0.f, q = 0.f;
    if (t < 16) { float2 v = part[bl * 16 + t]; s = v.x; q = v.y; }
    #pragma unroll
    for (int o = 8; o > 0; o >>= 1) { s += __shfl_xor(s, o, 64); q += __shfl_xor(q, o, 64); }
    if (t == 0) {
        float mean = s / (float)SLAB;
        float var = q / (float)SLAB - mean * mean;
        stats[bl] = make_float2(mean, 1.f / sqrtf(var + 1e-5f));
    }
}

// ------- LN apply, bf16 out only -------
__global__ __launch_bounds__(256) void k_ln_apply(const float4* __restrict__ x,
                                                  const float2* __restrict__ stats,
                                                  ushort* __restrict__ ob) {
    long i = (long)blockIdx.x * 256 + threadIdx.x;
    int bl = (int)(i >> 16);
    float2 st = stats[bl];
    float4 v = x[i];
    uint2 ow;
    ow.x = pack2((v.x - st.x) * st.y, (v.y - st.x) * st.y);
    ow.y = pack2((v.z - st.x) * st.y, (v.w - st.x) * st.y);
    ((uint2*)ob)[i] = ow;
}

// ------- final normalize + transpose back to [b][c][n][l] -------
__global__ __launch_bounds__(256) void k_out(const float* __restrict__ x,
                                             const float2* __restrict__ stats,
                                             float* __restrict__ out) {
    int n = blockIdx.x, b = blockIdx.y, c = threadIdx.x;
    float v[12];
    #pragma unroll
    for (int l = 0; l < 12; l++) {
        float2 st = stats[b * 12 + l];
        float t = x[(long)(b * 12 + l) * SLAB + (long)n * 256 + c];
        v[l] = (t - st.x) * st.y;
    }
    float4* op = (float4*)(out + ((long)(b * 256 + c) * 1024 + n) * 12);
    op[0] = make_float4(v[0], v[1], v[2], v[3]);
    op[1] = make_float4(v[4], v[5], v[6], v[7]);
    op[2] = make_float4(v[8], v[9], v[10], v[11]);
}

// =================================================================
extern "C" void kernel_launch(void* const* d_in, const int* in_sizes, int n_in,
                              void* d_out, int out_size, void* d_ws, size_t ws_size,
                              hipStream_t stream) {
    (void)in_sizes; (void)n_in; (void)out_size; (void)ws_size;
    const float* x_in = (const float*)d_in[0];
    const int*   dg   = (const int*)d_in[1];
    const float* nv1  = (const float*)d_in[2];
    const float* nv2  = (const float*)d_in[3];
    const float* Wmlp = (const float*)d_in[4];
    const float* bmlp = (const float*)d_in[5];
    const float* Wg0  = (const float*)d_in[6];
    const float* ag0  = (const float*)d_in[7];
    const float* Wgo  = (const float*)d_in[8];
    const float* ago  = (const float*)d_in[9];
    const float* Wg1  = (const float*)d_in[10];
    const float* bg1  = (const float*)d_in[11];
    const float* Wg2  = (const float*)d_in[12];
    const float* bg2  = (const float*)d_in[13];
    const float* Wg3  = (const float*)d_in[14];
    const float* bg3  = (const float*)d_in[15];
    const float* alpha = (const float*)d_in[16];
    const float* wgt  = (const float*)d_in[17];
    const float* bia  = (const float*)d_in[18];
    float* out = (float*)d_out;

    // ---- workspace (~208 MB; Af aliases the dead U1+U2 region) ----
    float* XTf = (float*)d_ws;          // fp32 x_in copy
    float* Bf  = XTf + TOT;             // fp32 gcn; later final pre-LN
    ushort* U1 = (ushort*)(Bf + TOT);   // Xb bf16
    ushort* U2 = U1 + TOT;              // XTT; later g (attn1 out)
    float* Af  = (float*)U1;            // fp32 fuse output, live after U1/U2 dead
    ushort* U3 = U2 + TOT;              // x1b; later xn bf16
    ushort* U4 = U3 + TOT;              // WhT; later h bf16
    ushort* ADPB = U4 + TOT;            // [1024][1024]
    ushort* WMLPB = ADPB + (long)1024 * 1024;
    ushort* WG0T = WMLPB + 131072;
    ushort* WGOT = WG0T + 65536;
    ushort* WGIB = WGOT + 65536;        // [512][256] interleaved g1/g2
    ushort* WG3B = WGIB + 131072;
    float* BIASI = (float*)(WG3B + 65536);  // 512
    float* VA = BIASI + 512;                // 1024
    float* W1V = VA + 1024;
    float* W2V = W1V + 49152;
    float* W2M = W2V + 49152;               // 48 (+pad)
    uint* MASKW = (uint*)(W2M + 64);        // 32768
    float2* PART = (float2*)(MASKW + 32768); // [48][16]
    float2* STATS1 = PART + 48 * 16;
    float2* STATS2 = STATS1 + 48;
    float* WT = (float*)(STATS2 + 48);
    float* BT2 = WT + SLAB;

    dim3 blk(256);
    // prep
    k_wt2<<<dim3(4, 4, 2), blk, 0, stream>>>(Wg0, WG0T, Wgo, WGOT);
    k_wconv<<<512, blk, 0, stream>>>(Wmlp, WMLPB);
    k_wconv<<<256, blk, 0, stream>>>(Wg3, WG3B);
    k_wgi<<<512, blk, 0, stream>>>(Wg1, bg1, Wg2, bg2, WGIB, BIASI);
    k_va<<<256, blk, 0, stream>>>(Wg0, ag0, VA);
    k_va<<<256, blk, 0, stream>>>(Wgo, ago, VA + 512);
    k_wtprep<<<1024, blk, 0, stream>>>(wgt, bia, WT, BT2);
    k_adp<<<1024, blk, 0, stream>>>(nv1, nv2, ADPB);
    k_maskpack<<<128, blk, 0, stream>>>(dg, MASKW);
    k_tin<<<dim3(192, 4, 4), blk, 0, stream>>>(x_in, U1, XTf);
    k_xtt<<<dim3(16, 4, 48), blk, 0, stream>>>(U1, U2);
    // x1 = adp @ x  (Bt = XTT) -> U3 bf16
    k_bgemm<1, 0><<<dim3(8, 2, 48), blk, 0, stream>>>(ADPB, 0, nullptr, 0, 1024, 0, 1024,
        U2, SLAB, nullptr, nullptr, U3, SLAB, nullptr,
        nullptr, nullptr, nullptr, nullptr, nullptr);
    // gcn = [x|x1] @ Wmlp(o,c) + b -> Bf fp32
    k_bgemm<2, 0><<<dim3(8, 2, 48), blk, 0, stream>>>(U1, SLAB, U3, SLAB, 256, 256, 512,
        WMLPB, 0, bmlp, Bf, nullptr, SLAB, nullptr,
        nullptr, nullptr, nullptr, nullptr, nullptr);
    // GAT layer 1
    k_dots<<<12288, blk, 0, stream>>>(U1, VA, W1V, W2V);
    k_w2max<<<48, blk, 0, stream>>>(W2V, W2M);
    k_bgemm<1, 0><<<dim3(2, 8, 48), blk, 0, stream>>>(WG0T, 0, nullptr, 0, 256, 0, 256,
        U1, SLAB, nullptr, nullptr, U4, SLAB, nullptr,
        nullptr, nullptr, nullptr, nullptr, nullptr);
    k_attn_mf<0><<<768, blk, 0, stream>>>(U4, W1V, W2V, W2M, MASKW, U2,
                                          nullptr, nullptr, nullptr, nullptr, nullptr);
    // GAT layer 2
    k_dots<<<12288, blk, 0, stream>>>(U2, VA + 512, W1V, W2V);
    k_w2max<<<48, blk, 0, stream>>>(W2V, W2M);
    k_bgemm<1, 0><<<dim3(2, 8, 48), blk, 0, stream>>>(WGOT, 0, nullptr, 0, 256, 0, 256,
        U2, SLAB, nullptr, nullptr, U4, SLAB, nullptr,
        nullptr, nullptr, nullptr, nullptr, nullptr);
    // attn2 fused epilogue: Af = as*gat + bs*gcn + x, + LN1 partials
    k_attn_mf<1><<<768, blk, 0, stream>>>(U4, W1V, W2V, W2M, MASKW, nullptr,
                                          Bf, XTf, alpha, Af, PART);
    k_stats16<<<48, 64, 0, stream>>>(PART, STATS1);
    k_ln_apply<<<12288, blk, 0, stream>>>((const float4*)Af, STATS1, U3);
    // GLU pair GEMM (interleaved) -> U4 h bf16
    k_bgemm<1, 1><<<dim3(8, 4, 48), blk, 0, stream>>>(U3, SLAB, nullptr, 0, 256, 0, 256,
        WGIB, 0, nullptr, nullptr, U4, SLAB, BIASI,
        nullptr, nullptr, nullptr, nullptr, nullptr);
    // glu3 GEMM + finpre + LN2 partials -> Bf, PART
    k_bgemm<1, 2><<<dim3(8, 2, 48), blk, 0, stream>>>(U4, SLAB, nullptr, 0, 256, 0, 256,
        WG3B, 0, bg3, Bf, nullptr, SLAB, nullptr,
        Af, STATS1, WT, BT2, PART);
    k_stats16<<<48, 64, 0, stream>>>(PART, STATS2);
    k_out<<<dim3(1024, 4), blk, 0, stream>>>(Bf, STATS2, out);
}

// Round 15
// 485.896 us; speedup vs baseline: 1.3110x; 1.3110x over previous
//
#include <hip/hip_runtime.h>
#include <hip/hip_bf16.h>
#include <math.h>

#define DI __device__ __forceinline__
#define AS1 __attribute__((address_space(1)))
#define AS3 __attribute__((address_space(3)))

static constexpr int  B_ = 4, C_ = 256, N_ = 1024, L_ = 12, BL_ = 48;
static constexpr long SLAB = (long)N_ * C_;          // 262144 elems per (b,l)
static constexpr long TOT  = (long)BL_ * SLAB;       // 12,582,912 elems

typedef __attribute__((ext_vector_type(8))) short bf16x8;
typedef __attribute__((ext_vector_type(4))) float f32x4;
typedef __attribute__((ext_vector_type(4))) uint u32x4;

DI float b2f(uint hw) { return __builtin_bit_cast(float, (hw & 0xffffu) << 16); }
DI ushort f2b(float f) {
    uint u = __builtin_bit_cast(uint, f);
    u += 0x7FFFu + ((u >> 16) & 1u);
    return (ushort)(u >> 16);
}
DI uint pack2(float a, float b) {
    __hip_bfloat162 h = __float22bfloat162_rn(make_float2(a, b));
    uint r;
    __builtin_memcpy(&r, &h, 4);
    return r;
}
DI float fexp2(float x) {
#if __has_builtin(__builtin_amdgcn_exp2f)
    return __builtin_amdgcn_exp2f(x);
#else
    return __expf(x * 0.6931471805599453f);
#endif
}

DI void gload16(const void* g, void* l) {
    __builtin_amdgcn_global_load_lds((AS1 uint*)g, (AS3 uint*)l, 16, 0, 0);
}

// ---------------- block reductions (256 threads, 4 waves) ----------------
DI float block_sum256(float v, float* sc) {
    #pragma unroll
    for (int o = 32; o > 0; o >>= 1) v += __shfl_xor(v, o, 64);
    int wid = threadIdx.x >> 6;
    __syncthreads();
    if ((threadIdx.x & 63) == 0) sc[wid] = v;
    __syncthreads();
    return sc[0] + sc[1] + sc[2] + sc[3];
}
DI float block_max256(float v, float* sc) {
    #pragma unroll
    for (int o = 32; o > 0; o >>= 1) v = fmaxf(v, __shfl_xor(v, o, 64));
    int wid = threadIdx.x >> 6;
    __syncthreads();
    if ((threadIdx.x & 63) == 0) sc[wid] = v;
    __syncthreads();
    return fmaxf(fmaxf(sc[0], sc[1]), fmaxf(sc[2], sc[3]));
}

// ---------------- adp = softmax(relu(nv1@nv2), axis=1), bf16 out ----------------
__global__ __launch_bounds__(256) void k_adp(const float* __restrict__ nv1,
                                             const float* __restrict__ nv2,
                                             ushort* __restrict__ adp) {
    __shared__ float r[6];
    __shared__ float sc[4];
    int row = blockIdx.x, tid = threadIdx.x;
    if (tid < 6) r[tid] = nv1[row * 6 + tid];
    __syncthreads();
    float e[4];
    #pragma unroll
    for (int q = 0; q < 4; q++) {
        int j = tid + q * 256;
        float s = 0.f;
        #pragma unroll
        for (int k = 0; k < 6; k++) s += r[k] * nv2[k * 1024 + j];
        e[q] = s > 0.f ? s : 0.f;
    }
    float m = fmaxf(fmaxf(e[0], e[1]), fmaxf(e[2], e[3]));
    m = block_max256(m, sc);
    float ps = 0.f;
    #pragma unroll
    for (int q = 0; q < 4; q++) { e[q] = __expf(e[q] - m); ps += e[q]; }
    ps = block_sum256(ps, sc);
    float rinv = 1.f / ps;
    #pragma unroll
    for (int q = 0; q < 4; q++) adp[(long)row * 1024 + tid + q * 256] = f2b(e[q] * rinv);
}

// ------- transpose in: x[b][c][n][l] -> Xb[(b*12+l)][n][c] bf16 + fp32 copy -------
__global__ __launch_bounds__(256) void k_tin(const float* __restrict__ x,
                                             ushort* __restrict__ xb,
                                             float* __restrict__ xf) {
    __shared__ float t[64][65];
    int nl0 = blockIdx.x * 64, c0 = blockIdx.y * 64, b = blockIdx.z;
    int lx = threadIdx.x & 63, ly = threadIdx.x >> 6;
    #pragma unroll
    for (int i = 0; i < 16; i++) {
        int c = c0 + ly + i * 4;
        t[ly + i * 4][lx] = x[(long)(b * 256 + c) * 12288 + nl0 + lx];
    }
    __syncthreads();
    #pragma unroll
    for (int i = 0; i < 16; i++) {
        int nl = nl0 + ly + i * 4;
        int n = nl / 12, l = nl % 12;
        long idx = ((long)(b * 12 + l) * 1024 + n) * 256 + c0 + lx;
        float v = t[lx][ly + i * 4];
        xb[idx] = f2b(v);
        xf[idx] = v;
    }
}

// ---------------- per-bl transpose Xb[n][c] -> XTT[c][n] (bf16) ----------------
__global__ __launch_bounds__(256) void k_xtt(const ushort* __restrict__ X,
                                             ushort* __restrict__ XT) {
    __shared__ ushort t[64][68];
    int bl = blockIdx.z;
    int n0 = blockIdx.x * 64, c0 = blockIdx.y * 64;
    int lx = threadIdx.x & 63, ly = threadIdx.x >> 6;
    const ushort* Xp = X + (long)bl * SLAB;
    #pragma unroll
    for (int i = 0; i < 16; i++)
        t[ly + i * 4][lx] = Xp[(long)(n0 + ly + i * 4) * 256 + c0 + lx];
    __syncthreads();
    ushort* Tp = XT + (long)bl * SLAB;
    #pragma unroll
    for (int i = 0; i < 16; i++)
        Tp[(long)(c0 + ly + i * 4) * 1024 + n0 + lx] = t[lx][ly + i * 4];
}

// -------- GAT weight transposes 256x256 fp32 [c][o] -> bf16 [o][c] --------
__global__ __launch_bounds__(256) void k_wt2(const float* __restrict__ S0, ushort* __restrict__ D0,
                                             const float* __restrict__ S1, ushort* __restrict__ D1) {
    __shared__ float t[64][65];
    const float* S = blockIdx.z ? S1 : S0;
    ushort* D = blockIdx.z ? D1 : D0;
    int c0 = blockIdx.x * 64, o0 = blockIdx.y * 64;
    int lx = threadIdx.x & 63, ly = threadIdx.x >> 6;
    #pragma unroll
    for (int i = 0; i < 16; i++)
        t[ly + i * 4][lx] = S[(long)(c0 + ly + i * 4) * 256 + o0 + lx];
    __syncthreads();
    #pragma unroll
    for (int i = 0; i < 16; i++)
        D[(long)(o0 + ly + i * 4) * 256 + c0 + lx] = f2b(t[lx][ly + i * 4]);
}

// ---------------- fp32 -> bf16 straight cast ----------------
__global__ __launch_bounds__(256) void k_wconv(const float* __restrict__ S, ushort* __restrict__ D) {
    long i = (long)blockIdx.x * 256 + threadIdx.x;
    D[i] = f2b(S[i]);
}

// ------- interleaved GLU weights: WGI[p*32+q] = (q<16 ? Wg1 : Wg2) row p*16+q%16 -------
__global__ __launch_bounds__(256) void k_wgi(const float* __restrict__ W1, const float* __restrict__ b1,
                                             const float* __restrict__ W2, const float* __restrict__ b2,
                                             ushort* __restrict__ WGI, float* __restrict__ BI) {
    int n = blockIdx.x, p = n >> 5, q = n & 31;
    const float* src = (q < 16) ? W1 + (long)(p * 16 + q) * 256
                                : W2 + (long)(p * 16 + q - 16) * 256;
    WGI[(long)n * 256 + threadIdx.x] = f2b(src[threadIdx.x]);
    if (threadIdx.x == 0) BI[n] = (q < 16) ? b1[p * 16 + q] : b2[p * 16 + q - 16];
}

// ----- va = W @ a pair -----
__global__ __launch_bounds__(256) void k_va(const float* __restrict__ W, const float* __restrict__ a,
                                            float* __restrict__ va) {
    __shared__ float sc[4];
    int c = blockIdx.x, t = threadIdx.x;
    float w = W[(long)c * 256 + t];
    float s1 = block_sum256(w * a[t], sc);
    float s2 = block_sum256(w * a[256 + t], sc);
    if (t == 0) { va[c] = s1; va[256 + c] = s2; }
}

// ------- weight/bias prep: wt[n][c] = w[c][n]+1, bt[n][c] = b[c][n] -------
__global__ __launch_bounds__(256) void k_wtprep(const float* __restrict__ w,
                                                const float* __restrict__ b,
                                                float* __restrict__ wt,
                                                float* __restrict__ bt) {
    int n = blockIdx.x, c = threadIdx.x;
    wt[(long)n * 256 + c] = w[(long)c * 1024 + n] + 1.f;
    bt[(long)n * 256 + c] = b[(long)c * 1024 + n];
}

// ------- pack mask bits -------
__global__ __launch_bounds__(256) void k_maskpack(const int* __restrict__ dg,
                                                  uint* __restrict__ maskw) {
    int w = blockIdx.x * 256 + threadIdx.x;
    int row = w >> 5, wo = w & 31;
    uint m = 0;
    #pragma unroll
    for (int b = 0; b < 32; b++)
        m |= (dg[(long)row * 1024 + wo * 32 + b] > 0 ? 1u : 0u) << b;
    maskw[w] = m;
}

// ------- bf16 MFMA GEMM, 2-phase pipelined -------
// GLU=0: plain (+bias) -> Cf/Cb. GLU=1: interleaved g1/g2, h=g1*sig(g2) -> Cb.
// GLU=2: finpre fusion: v=(acc+bias + (FA-m1)*r1)*WTp + BTp -> Cf, + LN partials.
template<int NPAIR, int GLU>
__global__ __launch_bounds__(256) void k_bgemm(
    const ushort* __restrict__ A0, long sA0,
    const ushort* __restrict__ A1, long sA1,
    int lda, int K0, int KK,
    const ushort* __restrict__ Bt, long sBt,
    const float* __restrict__ bias,
    float* __restrict__ Cf, ushort* __restrict__ Cb, long sC,
    const float* __restrict__ biasi,
    const float* __restrict__ FA, const float2* __restrict__ ST1,
    const float* __restrict__ WTp, const float* __restrict__ BTp,
    float2* __restrict__ partOut) {
    __shared__ ushort As[2][128 * 32];
    __shared__ ushort Bs[2][128 * 32];
    __shared__ float sc[4];
    const int tid = threadIdx.x;
    const int bl = blockIdx.z;
    const int m0 = blockIdx.x * 128, n0 = blockIdx.y * 128;
    const int N = gridDim.y * 128;
    const int lane = tid & 63, w = tid >> 6;
    const int wm = (w >> 1) * 64, wn = (w & 1) * 64;
    const int sr = tid >> 2, sk = (tid & 3) * 8;
    const int fr = lane & 15, fk = (lane >> 4) * 8;
    f32x4 acc[4][4] = {};
    const ushort* Ab0 = A0 + (long)bl * sA0;
    const ushort* Ab1 = (NPAIR == 2) ? A1 + (long)bl * sA1 : nullptr;
    const ushort* Bb = Bt + (long)bl * sBt;

    auto stage = [&](int buf, int k0) {
        const ushort* Asrc = Ab0; int kl = k0;
        if (NPAIR == 2 && k0 >= K0) { Asrc = Ab1; kl = k0 - K0; }
        gload16(&Asrc[(long)(m0 + sr) * lda + kl + sk],      &As[buf][sr * 32 + sk]);
        gload16(&Asrc[(long)(m0 + sr + 64) * lda + kl + sk], &As[buf][(sr + 64) * 32 + sk]);
        gload16(&Bb[(long)(n0 + sr) * KK + k0 + sk],         &Bs[buf][sr * 32 + sk]);
        gload16(&Bb[(long)(n0 + sr + 64) * KK + k0 + sk],    &Bs[buf][(sr + 64) * 32 + sk]);
    };
    auto compute = [&](int buf) {
        bf16x8 af[4], bg[4];
        #pragma unroll
        for (int i = 0; i < 4; i++) {
            af[i] = *(const bf16x8*)&As[buf][(wm + i * 16 + fr) * 32 + fk];
            bg[i] = *(const bf16x8*)&Bs[buf][(wn + i * 16 + fr) * 32 + fk];
        }
        #pragma unroll
        for (int i = 0; i < 4; i++)
            #pragma unroll
            for (int j = 0; j < 4; j++)
                acc[i][j] = __builtin_amdgcn_mfma_f32_16x16x32_bf16(af[i], bg[j], acc[i][j], 0, 0, 0);
    };

    stage(0, 0);
    __syncthreads();
    int cur = 0;
    for (int k0 = 32; k0 < KK; k0 += 32) {
        stage(cur ^ 1, k0);
        compute(cur);
        __syncthreads();
        cur ^= 1;
    }
    compute(cur);

    const int cn = lane & 15, rb = (lane >> 4) * 4;
    if (GLU == 1) {
        #pragma unroll
        for (int nt = 0; nt < 4; nt += 2) {
            int n1 = n0 + wn + nt * 16 + cn;
            int hcol = ((n1 >> 5) << 4) + cn;
            float b1 = biasi[n1], b2 = biasi[n1 + 16];
            #pragma unroll
            for (int i = 0; i < 4; i++) {
                #pragma unroll
                for (int r = 0; r < 4; r++) {
                    int m = m0 + wm + i * 16 + rb + r;
                    float g1 = acc[i][nt][r] + b1;
                    float g2 = acc[i][nt + 1][r] + b2;
                    float h = g1 / (1.f + __expf(-g2));
                    Cb[(long)bl * sC + (long)m * 256 + hcol] = f2b(h);
                }
            }
        }
    } else if (GLU == 2) {
        float2 st = ST1[bl];
        float ssum = 0.f, qsum = 0.f;
        #pragma unroll
        for (int j = 0; j < 4; j++) {
            int n = n0 + wn + j * 16 + cn;
            float bv = bias[n];
            #pragma unroll
            for (int i = 0; i < 4; i++) {
                #pragma unroll
                for (int r = 0; r < 4; r++) {
                    int m = m0 + wm + i * 16 + rb + r;
                    long idx = (long)bl * sC + (long)m * N + n;
                    float xn = (FA[idx] - st.x) * st.y;
                    float v = (acc[i][j][r] + bv + xn) * WTp[m * 256 + n] + BTp[m * 256 + n];
                    Cf[idx] = v;
                    ssum += v;
                    qsum += v * v;
                }
            }
        }
        ssum = block_sum256(ssum, sc);
        qsum = block_sum256(qsum, sc);
        if (tid == 0)
            partOut[bl * 16 + blockIdx.x * 2 + blockIdx.y] = make_float2(ssum, qsum);
    } else {
        #pragma unroll
        for (int j = 0; j < 4; j++) {
            int n = n0 + wn + j * 16 + cn;
            float bv = bias ? bias[n] : 0.f;
            #pragma unroll
            for (int i = 0; i < 4; i++) {
                #pragma unroll
                for (int r = 0; r < 4; r++) {
                    int m = m0 + wm + i * 16 + rb + r;
                    float v = acc[i][j][r] + bv;
                    long idx = (long)bl * sC + (long)m * N + n;
                    if (Cf) Cf[idx] = v;
                    if (Cb) Cb[idx] = f2b(v);
                }
            }
        }
    }
}

// ---------------- w1/w2 GEMV ----------------
__global__ __launch_bounds__(256) void k_dots(const ushort* __restrict__ X,
                                              const float* __restrict__ va,
                                              float* __restrict__ o1,
                                              float* __restrict__ o2) {
    int wid = threadIdx.x >> 6, lane = threadIdx.x & 63;
    long row = (long)blockIdx.x * 4 + wid;
    uint2 xv = *(const uint2*)(X + row * 256 + lane * 4);
    float x0 = b2f(xv.x), x1 = b2f(xv.x >> 16), x2 = b2f(xv.y), x3 = b2f(xv.y >> 16);
    float4 v1 = *(const float4*)&va[lane * 4];
    float4 v2 = *(const float4*)&va[256 + lane * 4];
    float s1 = x0 * v1.x + x1 * v1.y + x2 * v1.z + x3 * v1.w;
    float s2 = x0 * v2.x + x1 * v2.y + x2 * v2.z + x3 * v2.w;
    #pragma unroll
    for (int o = 32; o > 0; o >>= 1) { s1 += __shfl_xor(s1, o, 64); s2 += __shfl_xor(s2, o, 64); }
    if (lane == 0) { o1[row] = s1; o2[row] = s2; }
}

// ------- per-bl global max of w2 -------
__global__ __launch_bounds__(256) void k_w2max(const float* __restrict__ w2v,
                                               float* __restrict__ w2m) {
    __shared__ float sc[4];
    int bl = blockIdx.x;
    float4 v = *(const float4*)&w2v[(long)bl * 1024 + threadIdx.x * 4];
    float m = fmaxf(fmaxf(v.x, v.y), fmaxf(v.z, v.w));
    m = block_max256(m, sc);
    if (threadIdx.x == 0) w2m[bl] = m;
}

// One ks step with NAMED bg registers (rule #20), exp-free p, LUT AND, setprio MFMA.
#define PSTEP(KS_, B0, B1, B2, B3)                                             \
    do {                                                                       \
        const int ksv = (KS_);                                                 \
        float4 ea = *(const float4*)&w2E[ksv * 32 + fk8];                      \
        float4 eb = *(const float4*)&w2E[ksv * 32 + fk8 + 4];                  \
        float4 fa = *(const float4*)&w2F[ksv * 32 + fk8];                      \
        float4 fb = *(const float4*)&w2F[ksv * 32 + fk8 + 4];                  \
        _Pragma("unroll")                                                      \
        for (int mt = 0; mt < 4; mt++) {                                       \
            uint mby = (msk[(mt * 16 + fr) * 33 + ksv] >> fg8) & 0xffu;        \
            float p0 = fmaxf(c1[mt] * ea.x, c2[mt] * fa.x);                    \
            float p1 = fmaxf(c1[mt] * ea.y, c2[mt] * fa.y);                    \
            float p2 = fmaxf(c1[mt] * ea.z, c2[mt] * fa.z);                    \
            float p3 = fmaxf(c1[mt] * ea.w, c2[mt] * fa.w);                    \
            float p4 = fmaxf(c1[mt] * eb.x, c2[mt] * fb.x);                    \
            float p5 = fmaxf(c1[mt] * eb.y, c2[mt] * fb.y);                    \
            float p6 = fmaxf(c1[mt] * eb.z, c2[mt] * fb.z);                    \
            float p7 = fmaxf(c1[mt] * eb.w, c2[mt] * fb.w);                    \
            u32x4 av;                                                          \
            av[0] = pack2(p0, p1) & mlut[mby & 3];                             \
            av[1] = pack2(p2, p3) & mlut[(mby >> 2) & 3];                      \
            av[2] = pack2(p4, p5) & mlut[(mby >> 4) & 3];                      \
            av[3] = pack2(p6, p7) & mlut[(mby >> 6) & 3];                      \
            bf16x8 af = __builtin_bit_cast(bf16x8, av);                        \
            __builtin_amdgcn_s_setprio(1);                                     \
            acc_s[mt] = __builtin_amdgcn_mfma_f32_16x16x32_bf16(af, onesf, acc_s[mt], 0, 0, 0); \
            acc[mt][0] = __builtin_amdgcn_mfma_f32_16x16x32_bf16(af, B0, acc[mt][0], 0, 0, 0);  \
            acc[mt][1] = __builtin_amdgcn_mfma_f32_16x16x32_bf16(af, B1, acc[mt][1], 0, 0, 0);  \
            acc[mt][2] = __builtin_amdgcn_mfma_f32_16x16x32_bf16(af, B2, acc[mt][2], 0, 0, 0);  \
            acc[mt][3] = __builtin_amdgcn_mfma_f32_16x16x32_bf16(af, B3, acc[mt][3], 0, 0, 0);  \
            __builtin_amdgcn_s_setprio(0);                                     \
        }                                                                      \
    } while (0)

// ------- MFMA attention v10: barrier-free, exp-free, NAMED bg dbuf + setprio -------
// FUSE=1: epilogue computes as*elu(out)+bs*gcn+x -> Af fp32 + LN partials.
template<int FUSE>
__global__ __launch_bounds__(256, 3) void k_attn_mf(
    const ushort* __restrict__ WhT,   // [48][256][1024] bf16
    const float* __restrict__ w1v, const float* __restrict__ w2v,
    const float* __restrict__ w2m,    // [48]
    const uint* __restrict__ maskw,   // [1024][32]
    ushort* __restrict__ outB,
    const float* __restrict__ gcn, const float* __restrict__ xf,
    const float* __restrict__ alpha,
    float* __restrict__ outF, float2* __restrict__ part) {
    __shared__ float w2E[1024];          // exp2(w2 * log2e)
    __shared__ float w2F[1024];          // exp2(0.2 * w2 * log2e)
    __shared__ uint msk[64 * 33];        // padded stride 33
    __shared__ uint mlut[4];             // 2-bit mask -> halfword AND pattern
    __shared__ float sc[4];
    constexpr float LOG2E = 1.4426950408889634f;
    int d = blockIdx.x;                  // 768 blocks
    int lidx = (d & 7) * 96 + (d >> 3);  // XCD-chunked: 6 bl per XCD
    int bl = lidx >> 4;
    int i0 = (lidx & 15) * 64;
    int tid = threadIdx.x;
    #pragma unroll
    for (int q = 0; q < 4; q++) {
        float v = w2v[(long)bl * 1024 + tid + q * 256];
        w2E[tid + q * 256] = fexp2(v * LOG2E);
        w2F[tid + q * 256] = fexp2(v * (0.2f * LOG2E));
    }
    if (tid < 4) mlut[tid] = ((tid & 1) ? 0x0000FFFFu : 0u) | ((tid & 2) ? 0xFFFF0000u : 0u);
    {   // mask staging: 2048 words, coalesced, padded stride
        const uint4* gm = (const uint4*)(maskw + (long)i0 * 32);
        uint4 ma = gm[tid * 2], mb = gm[tid * 2 + 1];
        int r0 = tid >> 2, w0 = (tid & 3) * 8;
        uint* mp = &msk[r0 * 33 + w0];
        mp[0] = ma.x; mp[1] = ma.y; mp[2] = ma.z; mp[3] = ma.w;
        mp[4] = mb.x; mp[5] = mb.y; mp[6] = mb.z; mp[7] = mb.w;
    }
    __syncthreads();
    const int lane = tid & 63, w = tid >> 6;
    const int wn = w * 64;
    const int fr = lane & 15, fg = lane >> 4, fk8 = fg * 8;
    const int fg8 = fg * 8;
    const float w2mL = w2m[bl] * LOG2E;
    float c1[4], c2[4];
    #pragma unroll
    for (int mt = 0; mt < 4; mt++) {
        float w1L = w1v[(long)bl * 1024 + i0 + mt * 16 + fr] * LOG2E;
        float e0 = w1L + w2mL;
        float mrL = fmaxf(e0, 0.2f * e0);          // = log2e * leaky(w1+w2max) >= all scores
        c1[mt] = fexp2(w1L - mrL);
        c2[mt] = fexp2(0.2f * w1L - mrL);
    }
    f32x4 acc[4][4] = {};
    f32x4 acc_s[4] = {};
    u32x4 ov; ov[0] = ov[1] = ov[2] = ov[3] = 0x3F803F80u;   // bf16 1.0 pairs
    const bf16x8 onesf = __builtin_bit_cast(bf16x8, ov);
    const ushort* bp = WhT + (long)bl * SLAB;
    bf16x8 bgA0, bgA1, bgA2, bgA3, bgB0, bgB1, bgB2, bgB3;
    bgA0 = *(const bf16x8*)&bp[(long)(wn + 0 * 16 + fr) * 1024 + fk8];
    bgA1 = *(const bf16x8*)&bp[(long)(wn + 1 * 16 + fr) * 1024 + fk8];
    bgA2 = *(const bf16x8*)&bp[(long)(wn + 2 * 16 + fr) * 1024 + fk8];
    bgA3 = *(const bf16x8*)&bp[(long)(wn + 3 * 16 + fr) * 1024 + fk8];
    #pragma unroll 1
    for (int ks2 = 0; ks2 < 32; ks2 += 2) {
        {   // prefetch ks2+1 -> bgB*
            int kb = (ks2 + 1) * 32 + fk8;
            bgB0 = *(const bf16x8*)&bp[(long)(wn + 0 * 16 + fr) * 1024 + kb];
            bgB1 = *(const bf16x8*)&bp[(long)(wn + 1 * 16 + fr) * 1024 + kb];
            bgB2 = *(const bf16x8*)&bp[(long)(wn + 2 * 16 + fr) * 1024 + kb];
            bgB3 = *(const bf16x8*)&bp[(long)(wn + 3 * 16 + fr) * 1024 + kb];
        }
        PSTEP(ks2, bgA0, bgA1, bgA2, bgA3);
        if (ks2 + 2 < 32) {   // prefetch ks2+2 -> bgA*
            int kb = (ks2 + 2) * 32 + fk8;
            bgA0 = *(const bf16x8*)&bp[(long)(wn + 0 * 16 + fr) * 1024 + kb];
            bgA1 = *(const bf16x8*)&bp[(long)(wn + 1 * 16 + fr) * 1024 + kb];
            bgA2 = *(const bf16x8*)&bp[(long)(wn + 2 * 16 + fr) * 1024 + kb];
            bgA3 = *(const bf16x8*)&bp[(long)(wn + 3 * 16 + fr) * 1024 + kb];
        }
        PSTEP(ks2 + 1, bgB0, bgB1, bgB2, bgB3);
    }
    float as = 0.f, bs = 0.f, ssum = 0.f, qsum = 0.f;
    if (FUSE) { as = 1.f / (1.f + __expf(-alpha[0])); bs = 1.f - as; }
    #pragma unroll
    for (int mt = 0; mt < 4; mt++) {
        #pragma unroll
        for (int r = 0; r < 4; r++) {
            float si = 1.f / acc_s[mt][r];          // own row's sum — no cross-lane
            int i = mt * 16 + fg * 4 + r;
            #pragma unroll
            for (int nt = 0; nt < 4; nt++) {
                int c = wn + nt * 16 + fr;
                float v = acc[mt][nt][r] * si;
                v = (v > 0.f) ? v : __expf(v) - 1.f;       // elu
                long idx = (long)bl * SLAB + (long)(i0 + i) * 256 + c;
                if (FUSE) {
                    float fv = as * v + bs * gcn[idx] + xf[idx];
                    outF[idx] = fv;
                    ssum += fv;
                    qsum += fv * fv;
                } else {
                    outB[idx] = f2b(v);
                }
            }
        }
    }
    if (FUSE) {
        ssum = block_sum256(ssum, sc);
        qsum = block_sum256(qsum, sc);
        if (tid == 0) part[bl * 16 + (lidx & 15)] = make_float2(ssum, qsum);
    }
}

// ------- stats from 16 partials per slab -------
__global__ void k_stats16(const float2* __restrict__ part, float2* __restrict__ stats) {
    int bl = blockIdx.x, t = threadIdx.x;
    float s = 0.f, q = 0.f;
    if (t < 16) { float2 v = part[bl * 16 + t]; s = v.x; q = v.y; }
    #pragma unroll
    for (int o = 8; o > 0; o >>= 1) { s += __shfl_xor(s, o, 64); q += __shfl_xor(q, o, 64); }
    if (t == 0) {
        float mean = s / (float)SLAB;
        float var = q / (float)SLAB - mean * mean;
        stats[bl] = make_float2(mean, 1.f / sqrtf(var + 1e-5f));
    }
}

// ------- LN apply, bf16 out only -------
__global__ __launch_bounds__(256) void k_ln_apply(const float4* __restrict__ x,
                                                  const float2* __restrict__ stats,
                                                  ushort* __restrict__ ob) {
    long i = (long)blockIdx.x * 256 + threadIdx.x;
    int bl = (int)(i >> 16);
    float2 st = stats[bl];
    float4 v = x[i];
    uint2 ow;
    ow.x = pack2((v.x - st.x) * st.y, (v.y - st.x) * st.y);
    ow.y = pack2((v.z - st.x) * st.y, (v.w - st.x) * st.y);
    ((uint2*)ob)[i] = ow;
}

// ------- final normalize + transpose back to [b][c][n][l] -------
__global__ __launch_bounds__(256) void k_out(const float* __restrict__ x,
                                             const float2* __restrict__ stats,
                                             float* __restrict__ out) {
    int n = blockIdx.x, b = blockIdx.y, c = threadIdx.x;
    float v[12];
    #pragma unroll
    for (int l = 0; l < 12; l++) {
        float2 st = stats[b * 12 + l];
        float t = x[(long)(b * 12 + l) * SLAB + (long)n * 256 + c];
        v[l] = (t - st.x) * st.y;
    }
    float4* op = (float4*)(out + ((long)(b * 256 + c) * 1024 + n) * 12);
    op[0] = make_float4(v[0], v[1], v[2], v[3]);
    op[1] = make_float4(v[4], v[5], v[6], v[7]);
    op[2] = make_float4(v[8], v[9], v[10], v[11]);
}

// =================================================================
extern "C" void kernel_launch(void* const* d_in, const int* in_sizes, int n_in,
                              void* d_out, int out_size, void* d_ws, size_t ws_size,
                              hipStream_t stream) {
    (void)in_sizes; (void)n_in; (void)out_size; (void)ws_size;
    const float* x_in = (const float*)d_in[0];
    const int*   dg   = (const int*)d_in[1];
    const float* nv1  = (const float*)d_in[2];
    const float* nv2  = (const float*)d_in[3];
    const float* Wmlp = (const float*)d_in[4];
    const float* bmlp = (const float*)d_in[5];
    const float* Wg0  = (const float*)d_in[6];
    const float* ag0  = (const float*)d_in[7];
    const float* Wgo  = (const float*)d_in[8];
    const float* ago  = (const float*)d_in[9];
    const float* Wg1  = (const float*)d_in[10];
    const float* bg1  = (const float*)d_in[11];
    const float* Wg2  = (const float*)d_in[12];
    const float* bg2  = (const float*)d_in[13];
    const float* Wg3  = (const float*)d_in[14];
    const float* bg3  = (const float*)d_in[15];
    const float* alpha = (const float*)d_in[16];
    const float* wgt  = (const float*)d_in[17];
    const float* bia  = (const float*)d_in[18];
    float* out = (float*)d_out;

    // ---- workspace (~208 MB; Af aliases the dead U1+U2 region) ----
    float* XTf = (float*)d_ws;          // fp32 x_in copy
    float* Bf  = XTf + TOT;             // fp32 gcn; later final pre-LN
    ushort* U1 = (ushort*)(Bf + TOT);   // Xb bf16
    ushort* U2 = U1 + TOT;              // XTT; later g (attn1 out)
    float* Af  = (float*)U1;            // fp32 fuse output, live after U1/U2 dead
    ushort* U3 = U2 + TOT;              // x1b; later xn bf16
    ushort* U4 = U3 + TOT;              // WhT; later h bf16
    ushort* ADPB = U4 + TOT;            // [1024][1024]
    ushort* WMLPB = ADPB + (long)1024 * 1024;
    ushort* WG0T = WMLPB + 131072;
    ushort* WGOT = WG0T + 65536;
    ushort* WGIB = WGOT + 65536;        // [512][256] interleaved g1/g2
    ushort* WG3B = WGIB + 131072;
    float* BIASI = (float*)(WG3B + 65536);  // 512
    float* VA = BIASI + 512;                // 1024
    float* W1V = VA + 1024;
    float* W2V = W1V + 49152;
    float* W2M = W2V + 49152;               // 48 (+pad)
    uint* MASKW = (uint*)(W2M + 64);        // 32768
    float2* PART = (float2*)(MASKW + 32768); // [48][16]
    float2* STATS1 = PART + 48 * 16;
    float2* STATS2 = STATS1 + 48;
    float* WT = (float*)(STATS2 + 48);
    float* BT2 = WT + SLAB;

    dim3 blk(256);
    // prep
    k_wt2<<<dim3(4, 4, 2), blk, 0, stream>>>(Wg0, WG0T, Wgo, WGOT);
    k_wconv<<<512, blk, 0, stream>>>(Wmlp, WMLPB);
    k_wconv<<<256, blk, 0, stream>>>(Wg3, WG3B);
    k_wgi<<<512, blk, 0, stream>>>(Wg1, bg1, Wg2, bg2, WGIB, BIASI);
    k_va<<<256, blk, 0, stream>>>(Wg0, ag0, VA);
    k_va<<<256, blk, 0, stream>>>(Wgo, ago, VA + 512);
    k_wtprep<<<1024, blk, 0, stream>>>(wgt, bia, WT, BT2);
    k_adp<<<1024, blk, 0, stream>>>(nv1, nv2, ADPB);
    k_maskpack<<<128, blk, 0, stream>>>(dg, MASKW);
    k_tin<<<dim3(192, 4, 4), blk, 0, stream>>>(x_in, U1, XTf);
    k_xtt<<<dim3(16, 4, 48), blk, 0, stream>>>(U1, U2);
    // x1 = adp @ x  (Bt = XTT) -> U3 bf16
    k_bgemm<1, 0><<<dim3(8, 2, 48), blk, 0, stream>>>(ADPB, 0, nullptr, 0, 1024, 0, 1024,
        U2, SLAB, nullptr, nullptr, U3, SLAB, nullptr,
        nullptr, nullptr, nullptr, nullptr, nullptr);
    // gcn = [x|x1] @ Wmlp(o,c) + b -> Bf fp32
    k_bgemm<2, 0><<<dim3(8, 2, 48), blk, 0, stream>>>(U1, SLAB, U3, SLAB, 256, 256, 512,
        WMLPB, 0, bmlp, Bf, nullptr, SLAB, nullptr,
        nullptr, nullptr, nullptr, nullptr, nullptr);
    // GAT layer 1
    k_dots<<<12288, blk, 0, stream>>>(U1, VA, W1V, W2V);
    k_w2max<<<48, blk, 0, stream>>>(W2V, W2M);
    k_bgemm<1, 0><<<dim3(2, 8, 48), blk, 0, stream>>>(WG0T, 0, nullptr, 0, 256, 0, 256,
        U1, SLAB, nullptr, nullptr, U4, SLAB, nullptr,
        nullptr, nullptr, nullptr, nullptr, nullptr);
    k_attn_mf<0><<<768, blk, 0, stream>>>(U4, W1V, W2V, W2M, MASKW, U2,
                                          nullptr, nullptr, nullptr, nullptr, nullptr);
    // GAT layer 2
    k_dots<<<12288, blk, 0, stream>>>(U2, VA + 512, W1V, W2V);
    k_w2max<<<48, blk, 0, stream>>>(W2V, W2M);
    k_bgemm<1, 0><<<dim3(2, 8, 48), blk, 0, stream>>>(WGOT, 0, nullptr, 0, 256, 0, 256,
        U2, SLAB, nullptr, nullptr, U4, SLAB, nullptr,
        nullptr, nullptr, nullptr, nullptr, nullptr);
    // attn2 fused epilogue: Af = as*gat + bs*gcn + x, + LN1 partials
    k_attn_mf<1><<<768, blk, 0, stream>>>(U4, W1V, W2V, W2M, MASKW, nullptr,
                                          Bf, XTf, alpha, Af, PART);
    k_stats16<<<48, 64, 0, stream>>>(PART, STATS1);
    k_ln_apply<<<12288, blk, 0, stream>>>((const float4*)Af, STATS1, U3);
    // GLU pair GEMM (interleaved) -> U4 h bf16
    k_bgemm<1, 1><<<dim3(8, 4, 48), blk, 0, stream>>>(U3, SLAB, nullptr, 0, 256, 0, 256,
        WGIB, 0, nullptr, nullptr, U4, SLAB, BIASI,
        nullptr, nullptr, nullptr, nullptr, nullptr);
    // glu3 GEMM + finpre + LN2 partials -> Bf, PART
    k_bgemm<1, 2><<<dim3(8, 2, 48), blk, 0, stream>>>(U4, SLAB, nullptr, 0, 256, 0, 256,
        WG3B, 0, bg3, Bf, nullptr, SLAB, nullptr,
        Af, STATS1, WT, BT2, PART);
    k_stats16<<<48, 64, 0, stream>>>(PART, STATS2);
    k_out<<<dim3(1024, 4), blk, 0, stream>>>(Bf, STATS2, out);
}